// Round 15
// baseline (3191.495 us; speedup 1.0000x reference)
//
#include <hip/hip_runtime.h>

#define BB 256
#define TT 2048
#define HH 128
#define HP 136     // padded h1-row stride (f16) to break phase-B bank conflicts
#define G4 512
#define INW 4
#define OUTW 4
#define TC 56      // time-chunk (2048 = 36*56 + 32)
#define NT 512

typedef _Float16 f16x8 __attribute__((ext_vector_type(8)));
typedef float    f32x4 __attribute__((ext_vector_type(4)));

#define MFMA(A,B,C) __builtin_amdgcn_mfma_f32_16x16x32_f16((A),(B),(C),0,0,0)

__device__ __forceinline__ float sigm(float x)  { return __fdividef(1.f, 1.f + __expf(-x)); }
__device__ __forceinline__ float tanh_(float x) { return __fdividef(2.f, 1.f + __expf(-2.f*x)) - 1.f; }

// R14 post-mortem: absmax 8.544922e-02 == round-0's all-zero error exactly ->
// unwritten v slots, not bad numerics. The hoisted projection covered only
// t = i>>4 (0..31) but tc = 56. Fix: grid-stride t += 32. (part, o) decode is
// invariant under idx += 512, so shfl groups stay sound; trip count is
// wave-uniform (boundary 24 splits between waves 5 and 6).
// Layout (verified R11-R13): A-frag W-tile wrow_j = ((r&3)<<7)|(w<<4)|(j<<2)|(r>>2);
// B-frag h broadcast (wave-uniform); lane's acc j=r&3 selected by cndmask.

#define LDF(dst, wrj, kk) do {                                                 \
    const float* p_ = Mp_ + (size_t)(wrj) * HH + (kk)*32 + (kq << 3);          \
    const float4 lo_ = *(const float4*)p_;                                     \
    const float4 hi_ = *(const float4*)(p_ + 4);                               \
    dst = (f16x8){(_Float16)lo_.x,(_Float16)lo_.y,(_Float16)lo_.z,             \
                  (_Float16)lo_.w,(_Float16)hi_.x,(_Float16)hi_.y,             \
                  (_Float16)hi_.z,(_Float16)hi_.w}; } while (0)

#define LOADW(M) do { const float* Mp_ = (M);                                  \
    LDF(w00, wr0,      0); LDF(w01, wr0,      1); LDF(w02, wr0,      2); LDF(w03, wr0,      3); \
    LDF(w10, wr0 + 4,  0); LDF(w11, wr0 + 4,  1); LDF(w12, wr0 + 4,  2); LDF(w13, wr0 + 4,  3); \
    LDF(w20, wr0 + 8,  0); LDF(w21, wr0 + 8,  1); LDF(w22, wr0 + 8,  2); LDF(w23, wr0 + 8,  3); \
    LDF(w30, wr0 + 12, 0); LDF(w31, wr0 + 12, 1); LDF(w32, wr0 + 12, 2); LDF(w33, wr0 + 12, 3); \
} while (0)

#define RSTEP(HB) do {                                                         \
    f16x8 hv_;                                                                 \
    hv_ = *(const f16x8*)((HB) + (kq << 3));                                   \
    a0 = MFMA(w00, hv_, a0); a1 = MFMA(w10, hv_, a1);                          \
    a2 = MFMA(w20, hv_, a2); a3 = MFMA(w30, hv_, a3);                          \
    hv_ = *(const f16x8*)((HB) + 32 + (kq << 3));                              \
    a0 = MFMA(w01, hv_, a0); a1 = MFMA(w11, hv_, a1);                          \
    a2 = MFMA(w21, hv_, a2); a3 = MFMA(w31, hv_, a3);                          \
    hv_ = *(const f16x8*)((HB) + 64 + (kq << 3));                              \
    a0 = MFMA(w02, hv_, a0); a1 = MFMA(w12, hv_, a1);                          \
    a2 = MFMA(w22, hv_, a2); a3 = MFMA(w32, hv_, a3);                          \
    hv_ = *(const f16x8*)((HB) + 96 + (kq << 3));                              \
    a0 = MFMA(w03, hv_, a0); a1 = MFMA(w13, hv_, a1);                          \
    a2 = MFMA(w23, hv_, a2); a3 = MFMA(w33, hv_, a3); } while (0)

#define UPDSEL(CJ, HN) do {                                                    \
    f32x4 av_;                                                                 \
    _Pragma("unroll")                                                          \
    for (int e_ = 0; e_ < 4; ++e_) {                                           \
        const float t01_ = j1 ? a1[e_] : a0[e_];                               \
        const float t23_ = j1 ? a3[e_] : a2[e_];                               \
        av_[e_] = j2 ? t23_ : t01_;                                            \
    }                                                                          \
    const float i_ = sigm(av_[0]);                                             \
    const float f_ = sigm(av_[1]);                                             \
    const float g_ = tanh_(av_[2]);                                            \
    const float o_ = sigm(av_[3]);                                             \
    CJ = f_ * CJ + i_ * g_;                                                    \
    HN = o_ * tanh_(CJ); } while (0)

extern "C" __global__ void
__attribute__((amdgpu_flat_work_group_size(NT, NT)))
lstm2_fused(const float* __restrict__ x,
            const float* __restrict__ Wih0, const float* __restrict__ Whh0,
            const float* __restrict__ bih0, const float* __restrict__ bhh0,
            const float* __restrict__ Wih1, const float* __restrict__ Whh1,
            const float* __restrict__ bih1, const float* __restrict__ bhh1,
            const float* __restrict__ Wlin, const float* __restrict__ blin,
            float* __restrict__ out)
{
    // static LDS: 17,680 + 114,688 + 14,592 + 2,048 = 149,008 B
    __shared__ __align__(16) _Float16 h1h[(TC + 9) * HP]; // h1 ring (padded)
    __shared__ __align__(16) float    buf[TC * G4];       // xg0, then xg1
    __shared__ __align__(16) _Float16 h2r[(TC + 1) * HH]; // h2 ring
    __shared__ __align__(16) float    wlc[OUTW * HH];     // Wlin

    const int i    = threadIdx.x;
    const int w    = i >> 6;            // wave 0..7 -> tiles 4w..4w+3
    const int lane = i & 63;
    const int r    = lane & 15;
    const int kq   = lane >> 4;
    const int b    = blockIdx.x;

    const int wr0 = ((r & 3) << 7) | (r >> 2) | (w << 4);
    const bool j1 = (r & 1), j2 = (r & 2);
    const int  myu = (w << 4) | ((r & 3) << 2) | kq;
    const bool own = (r < 4);

    // ---- per-thread kernel-lifetime constants (rg == i is thread-constant)
    const int  rg_row = ((i & 3) << 7) | (i >> 2);        // W-row of gate-col i
    const float4 wv   = *(const float4*)(Wih0 + (size_t)rg_row * INW);
    const float  b0r  = bih0[rg_row] + bhh0[rg_row];
    const float  bb0  = bih1[wr0]      + bhh1[wr0];
    const float  bb1  = bih1[wr0 + 4]  + bhh1[wr0 + 4];
    const float  bb2  = bih1[wr0 + 8]  + bhh1[wr0 + 8];
    const float  bb3  = bih1[wr0 + 12] + bhh1[wr0 + 12];
    const int   po   = (i >> 2) & 3;                      // projection decode
    const int   part = i & 3;
    const float bl   = blin[po];

    wlc[i] = Wlin[i];                   // NT == OUTW*HH
    if (i < HH) { h1h[i] = (_Float16)0.f; h2r[i] = (_Float16)0.f; }

    float c1 = 0.f, c2 = 0.f;
    f16x8 w00, w01, w02, w03, w10, w11, w12, w13,
          w20, w21, w22, w23, w30, w31, w32, w33;

    const float* xb   = x   + (size_t)b * TT * INW;
    float*       vout = out + (size_t)b * TT * OUTW;
    float*       zout = out + (size_t)BB * TT * OUTW + (size_t)b * HH;

    for (int t0 = 0; t0 < TT; t0 += TC) {
        const int tc = (TT - t0 < TC) ? (TT - t0) : TC;

        if (t0 > 0 && i < HH) {                       // carry rings (prev full)
            h1h[i] = h1h[TC * HP + i];
            h2r[i] = h2r[TC * HH + i];
        }
        // xg0 bulk: buf[t][i] = b0r + Wih0[row].x_t  (x via L1 broadcast)
        for (int t = 0; t < tc; ++t) {
            const float4 xv = *(const float4*)(xb + (size_t)(t0 + t) * INW);
            buf[t * G4 + i] = b0r + wv.x*xv.x + wv.y*xv.y + wv.z*xv.z + wv.w*xv.w;
        }
        LOADW(Whh0);
        __syncthreads();

        // ================= Phase A: layer-0 recurrence =================
        for (int t = 0; t < tc; ++t) {
            const float* bp = buf + t * G4 + (w << 6) + (kq << 2);
            f32x4 a0 = *(const f32x4*)(bp);
            f32x4 a1 = *(const f32x4*)(bp + 16);
            f32x4 a2 = *(const f32x4*)(bp + 32);
            f32x4 a3 = *(const f32x4*)(bp + 48);
            RSTEP(h1h + t * HP);
            float hn;
            UPDSEL(c1, hn);
            if (own) h1h[(t + 1) * HP + myu] = (_Float16)hn;
            __syncthreads();
        }

        // ===== Phase B: xg1 = Wih1 @ h1 + b1 (bulk, A = h1 time-rows) =====
        LOADW(Wih1);
        const int ntb = (tc + 15) >> 4;
        for (int tb = 0; tb < ntb; ++tb) {
            f32x4 a0 = {0.f,0.f,0.f,0.f}, a1 = {0.f,0.f,0.f,0.f},
                  a2 = {0.f,0.f,0.f,0.f}, a3 = {0.f,0.f,0.f,0.f};
            const _Float16* ha = h1h + (tb * 16 + r + 1) * HP;
            f16x8 tv;
            tv = *(const f16x8*)(ha + (kq << 3));
            a0 = MFMA(tv, w00, a0); a1 = MFMA(tv, w10, a1);
            a2 = MFMA(tv, w20, a2); a3 = MFMA(tv, w30, a3);
            tv = *(const f16x8*)(ha + 32 + (kq << 3));
            a0 = MFMA(tv, w01, a0); a1 = MFMA(tv, w11, a1);
            a2 = MFMA(tv, w21, a2); a3 = MFMA(tv, w31, a3);
            tv = *(const f16x8*)(ha + 64 + (kq << 3));
            a0 = MFMA(tv, w02, a0); a1 = MFMA(tv, w12, a1);
            a2 = MFMA(tv, w22, a2); a3 = MFMA(tv, w32, a3);
            tv = *(const f16x8*)(ha + 96 + (kq << 3));
            a0 = MFMA(tv, w03, a0); a1 = MFMA(tv, w13, a1);
            a2 = MFMA(tv, w23, a2); a3 = MFMA(tv, w33, a3);
            #pragma unroll
            for (int e = 0; e < 4; ++e) {       // C row = local time
                const int tl = tb * 16 + (kq << 2) + e;
                if (tl < tc) {
                    float* bq = buf + tl * G4 + (w << 6) + r;
                    bq[0]  = a0[e] + bb0;
                    bq[16] = a1[e] + bb1;
                    bq[32] = a2[e] + bb2;
                    bq[48] = a3[e] + bb3;
                }
            }
        }
        __syncthreads();

        // ====== Phase C: layer-1 recurrence (projection hoisted out) ===
        LOADW(Whh1);
        for (int t = 0; t < tc; ++t) {
            const float* bp = buf + t * G4 + (w << 6) + (kq << 2);
            f32x4 a0 = *(const f32x4*)(bp);
            f32x4 a1 = *(const f32x4*)(bp + 16);
            f32x4 a2 = *(const f32x4*)(bp + 32);
            f32x4 a3 = *(const f32x4*)(bp + 48);
            RSTEP(h2r + t * HH);
            float hn;
            UPDSEL(c2, hn);
            if (own) {
                h2r[(t + 1) * HH + myu] = (_Float16)hn;
                if (t0 + t == TT - 1) zout[myu] = hn;   // z fp32-exact
            }
            __syncthreads();
        }

        // ====== bulk projection: v[t][o] = Wlin . h2[t] + bl ===========
        // 4 lanes per (t,o): lane decode (part, po) invariant under t += 32
        for (int t = i >> 4; t < tc; t += NT >> 4) {
            const f16x8*  hp = (const f16x8*)(h2r + (t + 1) * HH + part * 32);
            const float4* wp = (const float4*)(wlc + po * HH + part * 32);
            float s = 0.f;
            #pragma unroll
            for (int q = 0; q < 4; ++q) {            // 4 x 8 elems
                const f16x8 hv = hp[q];
                const float4 wa = wp[2*q], wb2 = wp[2*q + 1];
                s += (float)hv[0]*wa.x  + (float)hv[1]*wa.y
                   + (float)hv[2]*wa.z  + (float)hv[3]*wa.w
                   + (float)hv[4]*wb2.x + (float)hv[5]*wb2.y
                   + (float)hv[6]*wb2.z + (float)hv[7]*wb2.w;
            }
            s += __shfl_xor(s, 1);
            s += __shfl_xor(s, 2);
            if (part == 0) vout[(size_t)(t0 + t) * OUTW + po] = s + bl;
        }
        // chunk-top barrier (after carries/xg0) gates next chunk vs these reads
    }
}

extern "C" void kernel_launch(void* const* d_in, const int* in_sizes, int n_in,
                              void* d_out, int out_size, void* d_ws, size_t ws_size,
                              hipStream_t stream) {
    const float* x    = (const float*)d_in[0];
    const float* Wih0 = (const float*)d_in[1];
    const float* Whh0 = (const float*)d_in[2];
    const float* bih0 = (const float*)d_in[3];
    const float* bhh0 = (const float*)d_in[4];
    const float* Wih1 = (const float*)d_in[5];
    const float* Whh1 = (const float*)d_in[6];
    const float* bih1 = (const float*)d_in[7];
    const float* bhh1 = (const float*)d_in[8];
    const float* Wlin = (const float*)d_in[9];
    const float* blin = (const float*)d_in[10];
    float* out = (float*)d_out;

    lstm2_fused<<<dim3(BB), dim3(NT), 0, stream>>>(
        x, Wih0, Whh0, bih0, bhh0, Wih1, Whh1, bih1, bhh1, Wlin, blin, out);
}

// Round 16
// 3160.823 us; speedup vs baseline: 1.0097x; 1.0097x over previous
//
#include <hip/hip_runtime.h>

#define BB 256
#define TT 2048
#define HH 128
#define HP 136     // padded h1-row stride (f16): breaks phase-B bank conflicts
#define G4 512
#define INW 4
#define OUTW 4
#define TC 56      // time-chunk (2048 = 36*56 + 32, both even)
#define NT 512

typedef _Float16 f16x8 __attribute__((ext_vector_type(8)));
typedef float    f32x4 __attribute__((ext_vector_type(4)));

#define MFMA(A,B,C) __builtin_amdgcn_mfma_f32_16x16x32_f16((A),(B),(C),0,0,0)

__device__ __forceinline__ float sigm(float x)  { return __fdividef(1.f, 1.f + __expf(-x)); }
__device__ __forceinline__ float tanh_(float x) { return __fdividef(2.f, 1.f + __expf(-2.f*x)) - 1.f; }

// R15 post-mortem: projection hoist regressed (3048->3191); LDS pipe is the
// per-step bottleneck (~72 DS ops/CU/step: 32 h-reads + 32 acc-init reads +
// writes). R16: (a) in-step projection restored, Wlin/bias in REGISTERS (no
// wlc LDS); (b) MFMA with C=0 + post-select xg add: each lane's unit-gates are
// 4 contiguous floats (buf[t*512 + myu*4], layout verified for xg0 bulk AND
// phase-B writes) -> acc-init 4 ds_read_b128/wave -> 1. DS ~72 -> ~44 /CU/step.
// Layout (verified R11-R15): A-frag W-tile wrow_j = ((r&3)<<7)|(w<<4)|(j<<2)|(r>>2);
// B-frag h broadcast (wave-uniform); lane (r,kq) owns unit w*16+(r&3)*4+kq.

#define LDF(dst, wrj, kk) do {                                                 \
    const float* p_ = Mp_ + (size_t)(wrj) * HH + (kk)*32 + (kq << 3);          \
    const float4 lo_ = *(const float4*)p_;                                     \
    const float4 hi_ = *(const float4*)(p_ + 4);                               \
    dst = (f16x8){(_Float16)lo_.x,(_Float16)lo_.y,(_Float16)lo_.z,             \
                  (_Float16)lo_.w,(_Float16)hi_.x,(_Float16)hi_.y,             \
                  (_Float16)hi_.z,(_Float16)hi_.w}; } while (0)

#define LOADW(M) do { const float* Mp_ = (M);                                  \
    LDF(w00, wr0,      0); LDF(w01, wr0,      1); LDF(w02, wr0,      2); LDF(w03, wr0,      3); \
    LDF(w10, wr0 + 4,  0); LDF(w11, wr0 + 4,  1); LDF(w12, wr0 + 4,  2); LDF(w13, wr0 + 4,  3); \
    LDF(w20, wr0 + 8,  0); LDF(w21, wr0 + 8,  1); LDF(w22, wr0 + 8,  2); LDF(w23, wr0 + 8,  3); \
    LDF(w30, wr0 + 12, 0); LDF(w31, wr0 + 12, 1); LDF(w32, wr0 + 12, 2); LDF(w33, wr0 + 12, 3); \
} while (0)

#define RSTEP(HB) do {                                                         \
    f16x8 hv_;                                                                 \
    hv_ = *(const f16x8*)((HB) + (kq << 3));                                   \
    a0 = MFMA(w00, hv_, a0); a1 = MFMA(w10, hv_, a1);                          \
    a2 = MFMA(w20, hv_, a2); a3 = MFMA(w30, hv_, a3);                          \
    hv_ = *(const f16x8*)((HB) + 32 + (kq << 3));                              \
    a0 = MFMA(w01, hv_, a0); a1 = MFMA(w11, hv_, a1);                          \
    a2 = MFMA(w21, hv_, a2); a3 = MFMA(w31, hv_, a3);                          \
    hv_ = *(const f16x8*)((HB) + 64 + (kq << 3));                              \
    a0 = MFMA(w02, hv_, a0); a1 = MFMA(w12, hv_, a1);                          \
    a2 = MFMA(w22, hv_, a2); a3 = MFMA(w32, hv_, a3);                          \
    hv_ = *(const f16x8*)((HB) + 96 + (kq << 3));                              \
    a0 = MFMA(w03, hv_, a0); a1 = MFMA(w13, hv_, a1);                          \
    a2 = MFMA(w23, hv_, a2); a3 = MFMA(w33, hv_, a3); } while (0)

// select my tile (j = r&3) from the 4 acc vectors, add xg, LSTM update
#define UPDSEL(CJ, HN, XG) do {                                                \
    f32x4 av_;                                                                 \
    _Pragma("unroll")                                                          \
    for (int e_ = 0; e_ < 4; ++e_) {                                           \
        const float t01_ = j1 ? a1[e_] : a0[e_];                               \
        const float t23_ = j1 ? a3[e_] : a2[e_];                               \
        av_[e_] = (j2 ? t23_ : t01_) + (XG)[e_];                               \
    }                                                                          \
    const float i_ = sigm(av_[0]);                                             \
    const float f_ = sigm(av_[1]);                                             \
    const float g_ = tanh_(av_[2]);                                            \
    const float o_ = sigm(av_[3]);                                             \
    CJ = f_ * CJ + i_ * g_;                                                    \
    HN = o_ * tanh_(CJ); } while (0)

extern "C" __global__ void
__attribute__((amdgpu_flat_work_group_size(NT, NT)))
lstm2_fused(const float* __restrict__ x,
            const float* __restrict__ Wih0, const float* __restrict__ Whh0,
            const float* __restrict__ bih0, const float* __restrict__ bhh0,
            const float* __restrict__ Wih1, const float* __restrict__ Whh1,
            const float* __restrict__ bih1, const float* __restrict__ bhh1,
            const float* __restrict__ Wlin, const float* __restrict__ blin,
            float* __restrict__ out)
{
    // static LDS: 17,680 + 114,688 + 512 = 132,880 B
    __shared__ __align__(16) _Float16 h1h[(TC + 9) * HP]; // h1 ring (padded)
    __shared__ __align__(16) float    buf[TC * G4];       // xg0, then xg1
    __shared__ __align__(16) _Float16 h2h[2 * HH];        // h2 dbuf, parity t&1

    const int i    = threadIdx.x;
    const int w    = i >> 6;            // wave 0..7 -> tiles 4w..4w+3
    const int lane = i & 63;
    const int r    = lane & 15;
    const int kq   = lane >> 4;
    const int b    = blockIdx.x;

    const int wr0 = ((r & 3) << 7) | (r >> 2) | (w << 4);
    const bool j1 = (r & 1), j2 = (r & 2);
    const int  myu = (w << 4) | ((r & 3) << 2) | kq;
    const bool own = (r < 4);

    // ---- per-thread kernel-lifetime constants
    const int  rg_row = ((i & 3) << 7) | (i >> 2);        // W-row of gate-col i
    const float4 wv   = *(const float4*)(Wih0 + (size_t)rg_row * INW);
    const float  b0r  = bih0[rg_row] + bhh0[rg_row];
    const float  bb0  = bih1[wr0]      + bhh1[wr0];
    const float  bb1  = bih1[wr0 + 4]  + bhh1[wr0 + 4];
    const float  bb2  = bih1[wr0 + 8]  + bhh1[wr0 + 8];
    const float  bb3  = bih1[wr0 + 12] + bhh1[wr0 + 12];
    // in-step projection constants (threads 0..255: output o, lane-part l)
    const int   po = i >> 6;            // valid for i<256: o = wave index
    const int   pl = i & 63;
    const float wlA = (i < 256) ? Wlin[po * HH + pl]      : 0.f;
    const float wlB = (i < 256) ? Wlin[po * HH + 64 + pl] : 0.f;
    const float bl  = (i < 256) ? blin[po] : 0.f;

    if (i < HH) { h1h[i] = (_Float16)0.f; h2h[i] = (_Float16)0.f; }

    float c1 = 0.f, c2 = 0.f;
    f16x8 w00, w01, w02, w03, w10, w11, w12, w13,
          w20, w21, w22, w23, w30, w31, w32, w33;

    const float* xb   = x   + (size_t)b * TT * INW;
    float*       vout = out + (size_t)b * TT * OUTW;
    float*       zout = out + (size_t)BB * TT * OUTW + (size_t)b * HH;

    for (int t0 = 0; t0 < TT; t0 += TC) {
        const int tc = (TT - t0 < TC) ? (TT - t0) : TC;

        if (t0 > 0 && i < HH) h1h[i] = h1h[TC * HP + i];   // carry h1 ring
        // xg0 bulk: buf[t][i] = b0r + Wih0[row].x_t  (x via L1 broadcast)
        for (int t = 0; t < tc; ++t) {
            const float4 xv = *(const float4*)(xb + (size_t)(t0 + t) * INW);
            buf[t * G4 + i] = b0r + wv.x*xv.x + wv.y*xv.y + wv.z*xv.z + wv.w*xv.w;
        }
        LOADW(Whh0);
        __syncthreads();

        // ================= Phase A: layer-0 recurrence =================
        for (int t = 0; t < tc; ++t) {
            f32x4 a0 = {0.f,0.f,0.f,0.f}, a1 = {0.f,0.f,0.f,0.f},
                  a2 = {0.f,0.f,0.f,0.f}, a3 = {0.f,0.f,0.f,0.f};
            RSTEP(h1h + t * HP);
            const f32x4 xg = *(const f32x4*)(buf + t * G4 + (myu << 2));
            float hn;
            UPDSEL(c1, hn, xg);
            if (own) h1h[(t + 1) * HP + myu] = (_Float16)hn;
            __syncthreads();
        }

        // ===== Phase B: xg1 = Wih1 @ h1 + b1 (bulk, A = h1 time-rows) =====
        LOADW(Wih1);
        const int ntb = (tc + 15) >> 4;
        for (int tb = 0; tb < ntb; ++tb) {
            f32x4 a0 = {0.f,0.f,0.f,0.f}, a1 = {0.f,0.f,0.f,0.f},
                  a2 = {0.f,0.f,0.f,0.f}, a3 = {0.f,0.f,0.f,0.f};
            const _Float16* ha = h1h + (tb * 16 + r + 1) * HP;
            f16x8 tv;
            tv = *(const f16x8*)(ha + (kq << 3));
            a0 = MFMA(tv, w00, a0); a1 = MFMA(tv, w10, a1);
            a2 = MFMA(tv, w20, a2); a3 = MFMA(tv, w30, a3);
            tv = *(const f16x8*)(ha + 32 + (kq << 3));
            a0 = MFMA(tv, w01, a0); a1 = MFMA(tv, w11, a1);
            a2 = MFMA(tv, w21, a2); a3 = MFMA(tv, w31, a3);
            tv = *(const f16x8*)(ha + 64 + (kq << 3));
            a0 = MFMA(tv, w02, a0); a1 = MFMA(tv, w12, a1);
            a2 = MFMA(tv, w22, a2); a3 = MFMA(tv, w32, a3);
            tv = *(const f16x8*)(ha + 96 + (kq << 3));
            a0 = MFMA(tv, w03, a0); a1 = MFMA(tv, w13, a1);
            a2 = MFMA(tv, w23, a2); a3 = MFMA(tv, w33, a3);
            #pragma unroll
            for (int e = 0; e < 4; ++e) {       // C row = local time
                const int tl = tb * 16 + (kq << 2) + e;
                if (tl < tc) {
                    float* bq = buf + tl * G4 + (w << 6) + r;
                    bq[0]  = a0[e] + bb0;
                    bq[16] = a1[e] + bb1;
                    bq[32] = a2[e] + bb2;
                    bq[48] = a3[e] + bb3;
                }
            }
        }
        __syncthreads();

        // ====== Phase C: layer-1 recurrence + in-step projection ======
        LOADW(Whh1);
        for (int t = 0; t < tc; ++t) {
            const int rb = (t & 1) * HH, wbuf = rb ^ HH;
            f32x4 a0 = {0.f,0.f,0.f,0.f}, a1 = {0.f,0.f,0.f,0.f},
                  a2 = {0.f,0.f,0.f,0.f}, a3 = {0.f,0.f,0.f,0.f};
            RSTEP(h2h + rb);
            const f32x4 xg = *(const f32x4*)(buf + t * G4 + (myu << 2));
            float hn;
            UPDSEL(c2, hn, xg);
            if (own) {
                h2h[wbuf + myu] = (_Float16)hn;
                if (t0 + t == TT - 1) zout[myu] = hn;   // z fp32-exact
            }
            __syncthreads();
            if (i < 256) {              // v[b,t,:] from fresh h2 (regs wlA/wlB)
                float p2 = (float)h2h[wbuf + pl] * wlA
                         + (float)h2h[wbuf + 64 + pl] * wlB;
                p2 += __shfl_xor(p2, 32);
                p2 += __shfl_xor(p2, 16);
                p2 += __shfl_xor(p2, 8);
                p2 += __shfl_xor(p2, 4);
                p2 += __shfl_xor(p2, 2);
                p2 += __shfl_xor(p2, 1);
                if (pl == 0) vout[(size_t)(t0 + t) * OUTW + po] = p2 + bl;
            }
        }
        // chunk-top barrier (after carry/xg0) gates next chunk vs these reads
    }
}

extern "C" void kernel_launch(void* const* d_in, const int* in_sizes, int n_in,
                              void* d_out, int out_size, void* d_ws, size_t ws_size,
                              hipStream_t stream) {
    const float* x    = (const float*)d_in[0];
    const float* Wih0 = (const float*)d_in[1];
    const float* Whh0 = (const float*)d_in[2];
    const float* bih0 = (const float*)d_in[3];
    const float* bhh0 = (const float*)d_in[4];
    const float* Wih1 = (const float*)d_in[5];
    const float* Whh1 = (const float*)d_in[6];
    const float* bih1 = (const float*)d_in[7];
    const float* bhh1 = (const float*)d_in[8];
    const float* Wlin = (const float*)d_in[9];
    const float* blin = (const float*)d_in[10];
    float* out = (float*)d_out;

    lstm2_fused<<<dim3(BB), dim3(NT), 0, stream>>>(
        x, Wih0, Whh0, bih0, bhh0, Wih1, Whh1, bih1, bhh1, Wlin, blin, out);
}

// Round 17
// 2956.180 us; speedup vs baseline: 1.0796x; 1.0692x over previous
//
#include <hip/hip_runtime.h>

#define BB 256
#define TT 2048
#define HH 128
#define HP 136     // padded h1-row stride (f16): breaks phase-B bank conflicts
#define G4 512
#define INW 4
#define OUTW 4
#define TC 56      // time-chunk (2048 = 36*56 + 32, both even)
#define NT 512

typedef _Float16 f16x8 __attribute__((ext_vector_type(8)));
typedef float    f32x4 __attribute__((ext_vector_type(4)));

#define MFMA(A,B,C) __builtin_amdgcn_mfma_f32_16x16x32_f16((A),(B),(C),0,0,0)

__device__ __forceinline__ float sigm(float x)  { return __fdividef(1.f, 1.f + __expf(-x)); }
__device__ __forceinline__ float tanh_(float x) { return __fdividef(2.f, 1.f + __expf(-2.f*x)) - 1.f; }

// R15/R16 refuted the LDS-throughput theory (time invariant to DS ops and
// conflicts). The cost is per-interval LATENCY. Two items found on the
// critical path of every phase-C step:
//  1. vout global store: __syncthreads drains vmcnt(0) -> every step waits a
//     global write-ack (~300-400cyc). Fix: v -> LDS vbuf, ONE bulk store/chunk.
//  2. projection's 6-deep ds_permute chain ran after UPDSEL (slowest-wave
//     skew). Fix: pipeline by 1 step — at step t project h2[t-1] from the
//     stable read-buffer, overlapping the MFMA wait; per-chunk tail projects
//     the last step.
// Layout (verified R11-R16): A-frag W-tile wrow_j = ((r&3)<<7)|(w<<4)|(j<<2)|(r>>2);
// B-frag h broadcast (wave-uniform); lane (r,kq) owns unit w*16+(r&3)*4+kq.

#define LDF(dst, wrj, kk) do {                                                 \
    const float* p_ = Mp_ + (size_t)(wrj) * HH + (kk)*32 + (kq << 3);          \
    const float4 lo_ = *(const float4*)p_;                                     \
    const float4 hi_ = *(const float4*)(p_ + 4);                               \
    dst = (f16x8){(_Float16)lo_.x,(_Float16)lo_.y,(_Float16)lo_.z,             \
                  (_Float16)lo_.w,(_Float16)hi_.x,(_Float16)hi_.y,             \
                  (_Float16)hi_.z,(_Float16)hi_.w}; } while (0)

#define LOADW(M) do { const float* Mp_ = (M);                                  \
    LDF(w00, wr0,      0); LDF(w01, wr0,      1); LDF(w02, wr0,      2); LDF(w03, wr0,      3); \
    LDF(w10, wr0 + 4,  0); LDF(w11, wr0 + 4,  1); LDF(w12, wr0 + 4,  2); LDF(w13, wr0 + 4,  3); \
    LDF(w20, wr0 + 8,  0); LDF(w21, wr0 + 8,  1); LDF(w22, wr0 + 8,  2); LDF(w23, wr0 + 8,  3); \
    LDF(w30, wr0 + 12, 0); LDF(w31, wr0 + 12, 1); LDF(w32, wr0 + 12, 2); LDF(w33, wr0 + 12, 3); \
} while (0)

#define RSTEP(HB) do {                                                         \
    f16x8 hv_;                                                                 \
    hv_ = *(const f16x8*)((HB) + (kq << 3));                                   \
    a0 = MFMA(w00, hv_, a0); a1 = MFMA(w10, hv_, a1);                          \
    a2 = MFMA(w20, hv_, a2); a3 = MFMA(w30, hv_, a3);                          \
    hv_ = *(const f16x8*)((HB) + 32 + (kq << 3));                              \
    a0 = MFMA(w01, hv_, a0); a1 = MFMA(w11, hv_, a1);                          \
    a2 = MFMA(w21, hv_, a2); a3 = MFMA(w31, hv_, a3);                          \
    hv_ = *(const f16x8*)((HB) + 64 + (kq << 3));                              \
    a0 = MFMA(w02, hv_, a0); a1 = MFMA(w12, hv_, a1);                          \
    a2 = MFMA(w22, hv_, a2); a3 = MFMA(w32, hv_, a3);                          \
    hv_ = *(const f16x8*)((HB) + 96 + (kq << 3));                              \
    a0 = MFMA(w03, hv_, a0); a1 = MFMA(w13, hv_, a1);                          \
    a2 = MFMA(w23, hv_, a2); a3 = MFMA(w33, hv_, a3); } while (0)

// select my tile (j = r&3) from the 4 acc vectors, add xg, LSTM update
#define UPDSEL(CJ, HN, XG) do {                                                \
    f32x4 av_;                                                                 \
    _Pragma("unroll")                                                          \
    for (int e_ = 0; e_ < 4; ++e_) {                                           \
        const float t01_ = j1 ? a1[e_] : a0[e_];                               \
        const float t23_ = j1 ? a3[e_] : a2[e_];                               \
        av_[e_] = (j2 ? t23_ : t01_) + (XG)[e_];                               \
    }                                                                          \
    const float i_ = sigm(av_[0]);                                             \
    const float f_ = sigm(av_[1]);                                             \
    const float g_ = tanh_(av_[2]);                                            \
    const float o_ = sigm(av_[3]);                                             \
    CJ = f_ * CJ + i_ * g_;                                                    \
    HN = o_ * tanh_(CJ); } while (0)

// projection of the h2 snapshot at LDS offset OFS into vbuf slot VT (waves 0-3)
#define PROJ(OFS, VT) do {                                                     \
    if (i < 256) {                                                             \
        float p2 = (float)h2h[(OFS) + pl] * wlA                                \
                 + (float)h2h[(OFS) + 64 + pl] * wlB;                          \
        p2 += __shfl_xor(p2, 32);                                              \
        p2 += __shfl_xor(p2, 16);                                              \
        p2 += __shfl_xor(p2, 8);                                               \
        p2 += __shfl_xor(p2, 4);                                               \
        p2 += __shfl_xor(p2, 2);                                               \
        p2 += __shfl_xor(p2, 1);                                               \
        if (pl == 0) vbuf[(VT) * OUTW + po] = p2 + bl;                         \
    } } while (0)

extern "C" __global__ void
__attribute__((amdgpu_flat_work_group_size(NT, NT)))
lstm2_fused(const float* __restrict__ x,
            const float* __restrict__ Wih0, const float* __restrict__ Whh0,
            const float* __restrict__ bih0, const float* __restrict__ bhh0,
            const float* __restrict__ Wih1, const float* __restrict__ Whh1,
            const float* __restrict__ bih1, const float* __restrict__ bhh1,
            const float* __restrict__ Wlin, const float* __restrict__ blin,
            float* __restrict__ out)
{
    // static LDS: 17,680 + 114,688 + 512 + 896 = 133,776 B
    __shared__ __align__(16) _Float16 h1h[(TC + 9) * HP]; // h1 ring (padded)
    __shared__ __align__(16) float    buf[TC * G4];       // xg0, then xg1
    __shared__ __align__(16) _Float16 h2h[2 * HH];        // h2 dbuf, parity t&1
    __shared__ __align__(16) float    vbuf[TC * OUTW];    // v staging (no vmcnt in-loop)

    const int i    = threadIdx.x;
    const int w    = i >> 6;            // wave 0..7 -> tiles 4w..4w+3
    const int lane = i & 63;
    const int r    = lane & 15;
    const int kq   = lane >> 4;
    const int b    = blockIdx.x;

    const int wr0 = ((r & 3) << 7) | (r >> 2) | (w << 4);
    const bool j1 = (r & 1), j2 = (r & 2);
    const int  myu = (w << 4) | ((r & 3) << 2) | kq;
    const bool own = (r < 4);

    // ---- per-thread kernel-lifetime constants
    const int  rg_row = ((i & 3) << 7) | (i >> 2);        // W-row of gate-col i
    const float4 wv   = *(const float4*)(Wih0 + (size_t)rg_row * INW);
    const float  b0r  = bih0[rg_row] + bhh0[rg_row];
    const float  bb0  = bih1[wr0]      + bhh1[wr0];
    const float  bb1  = bih1[wr0 + 4]  + bhh1[wr0 + 4];
    const float  bb2  = bih1[wr0 + 8]  + bhh1[wr0 + 8];
    const float  bb3  = bih1[wr0 + 12] + bhh1[wr0 + 12];
    // projection constants (threads 0..255: output o = wave, lane-part l)
    const int   po = i >> 6;
    const int   pl = i & 63;
    const float wlA = (i < 256) ? Wlin[po * HH + pl]      : 0.f;
    const float wlB = (i < 256) ? Wlin[po * HH + 64 + pl] : 0.f;
    const float bl  = (i < 256) ? blin[po] : 0.f;

    if (i < HH) { h1h[i] = (_Float16)0.f; h2h[i] = (_Float16)0.f; }

    float c1 = 0.f, c2 = 0.f;
    f16x8 w00, w01, w02, w03, w10, w11, w12, w13,
          w20, w21, w22, w23, w30, w31, w32, w33;

    const float* xb   = x   + (size_t)b * TT * INW;
    float*       vout = out + (size_t)b * TT * OUTW;
    float*       zout = out + (size_t)BB * TT * OUTW + (size_t)b * HH;

    for (int t0 = 0; t0 < TT; t0 += TC) {
        const int tc = (TT - t0 < TC) ? (TT - t0) : TC;

        if (t0 > 0 && i < HH) h1h[i] = h1h[TC * HP + i];   // carry h1 ring
        // xg0 bulk: buf[t][i] = b0r + Wih0[row].x_t  (x via L1 broadcast)
        for (int t = 0; t < tc; ++t) {
            const float4 xv = *(const float4*)(xb + (size_t)(t0 + t) * INW);
            buf[t * G4 + i] = b0r + wv.x*xv.x + wv.y*xv.y + wv.z*xv.z + wv.w*xv.w;
        }
        LOADW(Whh0);
        __syncthreads();

        // ================= Phase A: layer-0 recurrence =================
        for (int t = 0; t < tc; ++t) {
            f32x4 a0 = {0.f,0.f,0.f,0.f}, a1 = {0.f,0.f,0.f,0.f},
                  a2 = {0.f,0.f,0.f,0.f}, a3 = {0.f,0.f,0.f,0.f};
            RSTEP(h1h + t * HP);
            const f32x4 xg = *(const f32x4*)(buf + t * G4 + (myu << 2));
            float hn;
            UPDSEL(c1, hn, xg);
            if (own) h1h[(t + 1) * HP + myu] = (_Float16)hn;
            __syncthreads();
        }

        // ===== Phase B: xg1 = Wih1 @ h1 + b1 (bulk, A = h1 time-rows) =====
        LOADW(Wih1);
        const int ntb = (tc + 15) >> 4;
        for (int tb = 0; tb < ntb; ++tb) {
            f32x4 a0 = {0.f,0.f,0.f,0.f}, a1 = {0.f,0.f,0.f,0.f},
                  a2 = {0.f,0.f,0.f,0.f}, a3 = {0.f,0.f,0.f,0.f};
            const _Float16* ha = h1h + (tb * 16 + r + 1) * HP;
            f16x8 tv;
            tv = *(const f16x8*)(ha + (kq << 3));
            a0 = MFMA(tv, w00, a0); a1 = MFMA(tv, w10, a1);
            a2 = MFMA(tv, w20, a2); a3 = MFMA(tv, w30, a3);
            tv = *(const f16x8*)(ha + 32 + (kq << 3));
            a0 = MFMA(tv, w01, a0); a1 = MFMA(tv, w11, a1);
            a2 = MFMA(tv, w21, a2); a3 = MFMA(tv, w31, a3);
            tv = *(const f16x8*)(ha + 64 + (kq << 3));
            a0 = MFMA(tv, w02, a0); a1 = MFMA(tv, w12, a1);
            a2 = MFMA(tv, w22, a2); a3 = MFMA(tv, w32, a3);
            tv = *(const f16x8*)(ha + 96 + (kq << 3));
            a0 = MFMA(tv, w03, a0); a1 = MFMA(tv, w13, a1);
            a2 = MFMA(tv, w23, a2); a3 = MFMA(tv, w33, a3);
            #pragma unroll
            for (int e = 0; e < 4; ++e) {       // C row = local time
                const int tl = tb * 16 + (kq << 2) + e;
                if (tl < tc) {
                    float* bq = buf + tl * G4 + (w << 6) + r;
                    bq[0]  = a0[e] + bb0;
                    bq[16] = a1[e] + bb1;
                    bq[32] = a2[e] + bb2;
                    bq[48] = a3[e] + bb3;
                }
            }
        }
        __syncthreads();

        // ====== Phase C: layer-1 recurrence; projection pipelined by 1 ==
        LOADW(Whh1);
        for (int t = 0; t < tc; ++t) {
            const int rb = (t & 1) * HH, wbuf2 = rb ^ HH;
            f32x4 a0 = {0.f,0.f,0.f,0.f}, a1 = {0.f,0.f,0.f,0.f},
                  a2 = {0.f,0.f,0.f,0.f}, a3 = {0.f,0.f,0.f,0.f};
            RSTEP(h2h + rb);
            // project h2[t-1] (same stable buffer) under the MFMA shadow
            if (t > 0) PROJ(rb, t - 1);
            const f32x4 xg = *(const f32x4*)(buf + t * G4 + (myu << 2));
            float hn;
            UPDSEL(c2, hn, xg);
            if (own) {
                h2h[wbuf2 + myu] = (_Float16)hn;
                if (t0 + t == TT - 1) zout[myu] = hn;   // once per kernel
            }
            __syncthreads();
        }
        // tail: project h2[tc-1] (sits at offset rb(tc) = (tc&1)*HH)
        PROJ((tc & 1) * HH, tc - 1);
        __syncthreads();
        // bulk v store: one vmcnt drain per chunk instead of per step
        for (int j = i; j < tc * OUTW; j += NT)
            vout[(size_t)t0 * OUTW + j] = vbuf[j];
        // chunk-top barrier (after carry/xg0) gates next chunk vs these reads
    }
}

extern "C" void kernel_launch(void* const* d_in, const int* in_sizes, int n_in,
                              void* d_out, int out_size, void* d_ws, size_t ws_size,
                              hipStream_t stream) {
    const float* x    = (const float*)d_in[0];
    const float* Wih0 = (const float*)d_in[1];
    const float* Whh0 = (const float*)d_in[2];
    const float* bih0 = (const float*)d_in[3];
    const float* bhh0 = (const float*)d_in[4];
    const float* Wih1 = (const float*)d_in[5];
    const float* Whh1 = (const float*)d_in[6];
    const float* bih1 = (const float*)d_in[7];
    const float* bhh1 = (const float*)d_in[8];
    const float* Wlin = (const float*)d_in[9];
    const float* blin = (const float*)d_in[10];
    float* out = (float*)d_out;

    lstm2_fused<<<dim3(BB), dim3(NT), 0, stream>>>(
        x, Wih0, Whh0, bih0, bhh0, Wih1, Whh1, bih1, bhh1, Wlin, blin, out);
}